// Round 1
// baseline (184.687 us; speedup 1.0000x reference)
//
#include <hip/hip_runtime.h>
#include <hip/hip_bf16.h>

// BlurDownsample: depthwise 4x4 FIR (separable taps [1,3,3,1]/8 each axis),
// stride-2 downsample, pad (1,1). x: [N,C,256,256] f32 -> y: [N,C,128,128] f32.
//
// Strategy: separable filter. h[r][ow] = x[r][2ow-1] + 3x[r][2ow] + 3x[r][2ow+1]
// + x[r][2ow+2]; y[oh][ow] = (h[2oh-1] + 3h[2oh] + 3h[2oh+1] + h[2oh+2]) / 64.
// One thread per output column; rolling 4-register vertical window so each new
// output row computes only 2 new h values. Memory-bound: ideal 536MB read +
// 134MB write.

constexpr int H  = 256;
constexpr int W  = 256;
constexpr int OH = 128;
constexpr int OW = 128;
constexpr int TILE = 32;                 // output rows per block
constexpr int TILES_PER_PLANE = OH / TILE;

__global__ __launch_bounds__(OW) void blur_down_kernel(
    const float* __restrict__ x, float* __restrict__ y) {
    const int b     = blockIdx.x;
    const int plane = b / TILES_PER_PLANE;
    const int tile  = b % TILES_PER_PLANE;
    const int ow    = threadIdx.x;       // 0..127, one output column per lane

    const float* __restrict__ xp = x + (size_t)plane * H * W;
    float* __restrict__ yp = y + (size_t)plane * OH * OW
                               + (size_t)(tile * TILE) * OW + ow;

    const int c0 = 2 * ow - 1;           // leftmost input column (may be -1)
    const bool lpad = (ow == 0);         // col -1 is zero pad
    const bool rpad = (ow == OW - 1);    // col 256 is zero pad

    // horizontal FIR for input row r (zero rows outside [0,H))
    auto hrow = [&](int r) -> float {
        if (r < 0 || r >= H) return 0.0f;
        const float* __restrict__ row = xp + (size_t)r * W;
        // middle pair (cols 2ow, 2ow+1) is 8B-aligned -> one float2 load
        const float2 m = *reinterpret_cast<const float2*>(row + c0 + 1);
        const float x0 = lpad ? 0.0f : row[c0];
        const float x3 = rpad ? 0.0f : row[c0 + 3];
        return (x0 + x3) + 3.0f * (m.x + m.y);
    };

    const int oh0 = tile * TILE;
    const int r0  = 2 * oh0 - 1;         // first input row of the window

    float h0 = hrow(r0);
    float h1 = hrow(r0 + 1);
    #pragma unroll 4
    for (int k = 0; k < TILE; ++k) {
        const float h2 = hrow(r0 + 2 * k + 2);
        const float h3 = hrow(r0 + 2 * k + 3);
        const float v  = ((h0 + h3) + 3.0f * (h1 + h2)) * (1.0f / 64.0f);
        yp[(size_t)k * OW] = v;
        h0 = h2;
        h1 = h3;
    }
}

extern "C" void kernel_launch(void* const* d_in, const int* in_sizes, int n_in,
                              void* d_out, int out_size, void* d_ws, size_t ws_size,
                              hipStream_t stream) {
    const float* x = (const float*)d_in[0];
    float* y = (float*)d_out;

    const int planes = in_sizes[0] / (H * W);    // N*C = 2048
    const int grid   = planes * TILES_PER_PLANE; // 8192 blocks

    hipLaunchKernelGGL(blur_down_kernel, dim3(grid), dim3(OW), 0, stream, x, y);
}

// Round 2
// 143.776 us; speedup vs baseline: 1.2845x; 1.2845x over previous
//
#include <hip/hip_runtime.h>
#include <hip/hip_bf16.h>

// BlurDownsample: depthwise 4x4 FIR (separable taps [1,3,3,1]/8 per axis),
// stride-2 downsample, pad (1,1). x: [N,C,256,256] f32 -> y: [N,C,128,128] f32.
//
// R2: wave-per-row layout. Lane t loads float4 = input cols 4t..4t+3 (one
// dwordx4 per row per wave, 1KB coalesced). Horizontal FIR edge values
// x[4t-1], x[4t+4] come from __shfl of neighbor lanes (no extra loads).
// Each lane owns output cols {2t, 2t+1}; vertical FIR via rolling 4-register
// window (2 new h-rows per output row); float2 store per output row.
// Per output row per lane: 2 loads + 1 store for 2 outputs.

constexpr int H  = 256;
constexpr int W  = 256;
constexpr int OH = 128;
constexpr int OW = 128;
constexpr int WAVES_PER_BLOCK = 4;           // 256 threads
constexpr int TILE = OH / WAVES_PER_BLOCK;   // 32 output rows per wave

__global__ __launch_bounds__(256) void blur_down_kernel(
    const float* __restrict__ x, float* __restrict__ y) {
    const int plane = blockIdx.x;
    const int wave  = threadIdx.x >> 6;
    const int lane  = threadIdx.x & 63;

    const float* __restrict__ xp = x + (size_t)plane * H * W;
    float* __restrict__ yp       = y + (size_t)plane * OH * OW;

    const int oh0 = wave * TILE;             // first output row of this wave
    const int r0  = 2 * oh0 - 1;             // first input row of the window

    // Horizontal FIR for input row r: lane's float4 covers cols 4t..4t+3.
    // he (for ow=2t)   = x[4t-1] + 3x[4t]   + 3x[4t+1] + x[4t+2]
    // ho (for ow=2t+1) = x[4t+1] + 3x[4t+2] + 3x[4t+3] + x[4t+4]
    auto hrow = [&](int r, float& he, float& ho) {
        if (r < 0 || r >= H) { he = 0.0f; ho = 0.0f; return; }
        const float4 v =
            *reinterpret_cast<const float4*>(xp + (size_t)r * W + lane * 4);
        float xm1 = __shfl_up(v.w, 1);       // col 4t-1 from lane t-1
        if (lane == 0) xm1 = 0.0f;           // col -1 is zero pad
        float xp4 = __shfl_down(v.x, 1);     // col 4t+4 from lane t+1
        if (lane == 63) xp4 = 0.0f;          // col 256 is zero pad
        he = (xm1 + v.z) + 3.0f * (v.x + v.y);
        ho = (v.y + xp4) + 3.0f * (v.z + v.w);
    };

    float h0e, h0o, h1e, h1o;
    hrow(r0,     h0e, h0o);
    hrow(r0 + 1, h1e, h1o);

    #pragma unroll 4
    for (int k = 0; k < TILE; ++k) {
        float h2e, h2o, h3e, h3o;
        hrow(r0 + 2 * k + 2, h2e, h2o);
        hrow(r0 + 2 * k + 3, h3e, h3o);
        float2 out;
        out.x = ((h0e + h3e) + 3.0f * (h1e + h2e)) * (1.0f / 64.0f);
        out.y = ((h0o + h3o) + 3.0f * (h1o + h2o)) * (1.0f / 64.0f);
        *reinterpret_cast<float2*>(yp + (size_t)(oh0 + k) * OW + 2 * lane) = out;
        h0e = h2e; h0o = h2o;
        h1e = h3e; h1o = h3o;
    }
}

extern "C" void kernel_launch(void* const* d_in, const int* in_sizes, int n_in,
                              void* d_out, int out_size, void* d_ws, size_t ws_size,
                              hipStream_t stream) {
    const float* x = (const float*)d_in[0];
    float* y = (float*)d_out;

    const int planes = in_sizes[0] / (H * W);   // N*C = 2048
    hipLaunchKernelGGL(blur_down_kernel, dim3(planes), dim3(256), 0, stream,
                       x, y);
}

// Round 4
// 130.860 us; speedup vs baseline: 1.4113x; 1.0987x over previous
//
#include <hip/hip_runtime.h>
#include <hip/hip_bf16.h>

// BlurDownsample: depthwise 4x4 FIR (separable taps [1,3,3,1]/8 per axis),
// stride-2 downsample, pad (1,1). x: [N,C,256,256] f32 -> y: [N,C,128,128] f32.
//
// R4 = R3 with the nontemporal store fixed (ext_vector_type instead of
// HIP_vector_type, which __builtin_nontemporal_store rejects):
//  - wave-per-row float4 loads + shfl neighbor exchange
//  - __launch_bounds__(256, 8): force VGPR<=64, 8 waves/SIMD resident
//  - branch-free row padding (clamped row index + uniform 0/1 mask)
//  - nontemporal float2 stores for y (streaming, no reuse)

constexpr int H  = 256;
constexpr int W  = 256;
constexpr int OH = 128;
constexpr int OW = 128;
constexpr int WAVES_PER_BLOCK = 4;           // 256 threads
constexpr int TILE = OH / WAVES_PER_BLOCK;   // 32 output rows per wave

typedef float f32x2 __attribute__((ext_vector_type(2)));

__global__ __launch_bounds__(256, 8) void blur_down_kernel(
    const float* __restrict__ x, float* __restrict__ y) {
    const int plane = blockIdx.x;
    const int wave  = threadIdx.x >> 6;
    const int lane  = threadIdx.x & 63;

    const float* __restrict__ xp = x + (size_t)plane * H * W + lane * 4;
    float* __restrict__ yp       = y + (size_t)plane * OH * OW + 2 * lane;

    const int oh0 = wave * TILE;             // first output row of this wave
    const int r0  = 2 * oh0 - 1;             // first input row of the window

    const float mL = (lane == 0)  ? 0.0f : 1.0f;  // col -1 zero pad
    const float mR = (lane == 63) ? 0.0f : 1.0f;  // col 256 zero pad

    // Horizontal FIR for input row r. Branch-free: clamp row, zero via mask.
    // he (ow=2t)   = x[4t-1] + 3x[4t]   + 3x[4t+1] + x[4t+2]
    // ho (ow=2t+1) = x[4t+1] + 3x[4t+2] + 3x[4t+3] + x[4t+4]
    auto hrow = [&](int r, float& he, float& ho) {
        const int rc  = min(max(r, 0), H - 1);
        const float m = (r == rc) ? 1.0f : 0.0f;   // wave-uniform row mask
        const float4 v =
            *reinterpret_cast<const float4*>(xp + (size_t)rc * W);
        const float xm1 = __shfl_up(v.w, 1) * mL;   // col 4t-1
        const float xp4 = __shfl_down(v.x, 1) * mR; // col 4t+4
        he = ((xm1 + v.z) + 3.0f * (v.x + v.y)) * m;
        ho = ((v.y + xp4) + 3.0f * (v.z + v.w)) * m;
    };

    float h0e, h0o, h1e, h1o;
    hrow(r0,     h0e, h0o);
    hrow(r0 + 1, h1e, h1o);

    #pragma unroll 4
    for (int k = 0; k < TILE; ++k) {
        float h2e, h2o, h3e, h3o;
        hrow(r0 + 2 * k + 2, h2e, h2o);
        hrow(r0 + 2 * k + 3, h3e, h3o);
        f32x2 out;
        out.x = ((h0e + h3e) + 3.0f * (h1e + h2e)) * (1.0f / 64.0f);
        out.y = ((h0o + h3o) + 3.0f * (h1o + h2o)) * (1.0f / 64.0f);
        __builtin_nontemporal_store(
            out, reinterpret_cast<f32x2*>(yp + (size_t)(oh0 + k) * OW));
        h0e = h2e; h0o = h2o;
        h1e = h3e; h1o = h3o;
    }
}

extern "C" void kernel_launch(void* const* d_in, const int* in_sizes, int n_in,
                              void* d_out, int out_size, void* d_ws, size_t ws_size,
                              hipStream_t stream) {
    const float* x = (const float*)d_in[0];
    float* y = (float*)d_out;

    const int planes = in_sizes[0] / (H * W);   // N*C = 2048
    hipLaunchKernelGGL(blur_down_kernel, dim3(planes), dim3(256), 0, stream,
                       x, y);
}